// Round 3
// baseline (527.723 us; speedup 1.0000x reference)
//
#include <hip/hip_runtime.h>
#include <math.h>

// SimpleRetention bf16 MFMA, round 6: full 8-phase schedule (m201 template).
//  - 256x256 tile, BK=64, 8 waves, LDS [buf][kk][256][32] double-buffered (128 KiB)
//  - 4 phases per K-tile: {ds_read frags || stage 1 unit -> barrier ->
//    lgkmcnt(0) -> setprio(1) -> 16 MFMA -> setprio(0) -> barrier}
//  - staging 4 units ahead, s_waitcnt vmcnt(6) once per tile (never 0 mid-loop)
//  - 16B-chunk XOR swizzle by (row>>1)&3 -> 2-way ds_read_b128 (free)
//  - stage 2: strictly-upper att blocks skipped; stage 4 operand swap.

typedef __attribute__((ext_vector_type(8))) short short8;
typedef __attribute__((ext_vector_type(4))) float f32x4;
typedef __attribute__((ext_vector_type(4))) unsigned short us4;

#define BM 256
#define BN 256
#define BK 64

static __device__ __forceinline__ unsigned short f2bf(float f) {
    unsigned int u = __float_as_uint(f);
    u += 0x7FFFu + ((u >> 16) & 1u);   // RNE
    return (unsigned short)(u >> 16);
}

static __device__ __forceinline__ void gload16(const unsigned short* g, unsigned short* l) {
    __builtin_amdgcn_global_load_lds(
        (const __attribute__((address_space(1))) unsigned int*)g,
        (__attribute__((address_space(3))) unsigned int*)l, 16, 0, 0);
}

// STAGE: 1 = merged QKV projection, 3 = att=(QK^T)*decay, 4 = out = att x V
template <int STAGE>
__global__ __launch_bounds__(512, 2)
void gemm_bt(const unsigned short* __restrict__ A,
             const unsigned short* __restrict__ Bt,
             void* __restrict__ Cv,
             unsigned short* __restrict__ Cq,
             unsigned short* __restrict__ Ck,
             unsigned short* __restrict__ Cvt,
             int lda, int ldb, int Kd,
             long long sA, long long sB, long long sC)
{
    constexpr int S = 2048, H = 2048;
    const int rowBase = blockIdx.y * BM;
    const int colBase = blockIdx.x * BN;

    if (STAGE == 3 && blockIdx.x > blockIdx.y) return; // never read by stage 4

    A  += (long long)blockIdx.z * sA;
    Bt += (long long)blockIdx.z * sB;

    // [buf][kk][row 0..255][32 elems]; 16B chunk c of row r stored at c^((r>>1)&3)
    __shared__ unsigned short As[32768];
    __shared__ unsigned short Bs[32768];

    const int tid  = threadIdx.x;
    const int wave = tid >> 6;
    const int lane = tid & 63;
    const int wm = (wave >> 2) * 128;  // 2 wave-rows x 128
    const int wn = (wave & 3) * 64;    // 4 wave-cols x 64

    f32x4 acc[8][4];
#pragma unroll
    for (int i = 0; i < 8; ++i)
#pragma unroll
        for (int j = 0; j < 4; ++j) acc[i][j] = (f32x4){0.f, 0.f, 0.f, 0.f};

    int kmax = Kd;
    if (STAGE == 4) kmax = rowBase + BM;  // causal: k = m <= n-block end
    const int nt = kmax >> 6;             // >= 4 in all stages

    // Staging: per unit (matrix, kk, tile): 512 thr x 2 gload16 of 16B.
    // lane -> row = wave*32 + g*16 + (lane>>2), chunk pos = lane&3,
    // source chunk = (lane&3) ^ ((lane>>3)&3)  [= pos ^ ((row>>1)&3)].
    const int lr  = lane >> 2;
    const int sc8 = ((lane & 3) ^ ((lane >> 3) & 3)) * 8;
    const unsigned short* gaS = A  + (size_t)(rowBase + wave * 32 + lr) * lda + sc8;
    const unsigned short* gbS = Bt + (size_t)(colBase + wave * 32 + lr) * ldb + sc8;
    unsigned short* lAw = As + wave * 1024;
    unsigned short* lBw = Bs + wave * 1024;

    const int fr = lane & 15;
    const int qd = lane >> 4;                    // k-quad within kk-half
    const int cq = (qd ^ ((fr >> 1) & 3)) * 8;   // swizzled elem offset in row

#define STG_A(t, kk, buf) do { \
    const unsigned short* _g = gaS + (t) * 64 + (kk) * 32; \
    unsigned short* _l = lAw + ((buf) * 2 + (kk)) * 8192; \
    gload16(_g, _l); gload16(_g + (size_t)16 * lda, _l + 512); } while (0)
#define STG_B(t, kk, buf) do { \
    const unsigned short* _g = gbS + (t) * 64 + (kk) * 32; \
    unsigned short* _l = lBw + ((buf) * 2 + (kk)) * 8192; \
    gload16(_g, _l); gload16(_g + (size_t)16 * ldb, _l + 512); } while (0)

    // prologue: tile 0 complete (buf 0) + tile 1 units S1..S3 (buf 1)
    STG_A(0, 0, 0); STG_B(0, 0, 0); STG_A(0, 1, 0); STG_B(0, 1, 0);
    STG_A(1, 0, 1); STG_B(1, 0, 1); STG_A(1, 1, 1);
    __builtin_amdgcn_sched_barrier(0);
    asm volatile("s_waitcnt vmcnt(6)" ::: "memory");  // tile 0 resident
    __builtin_amdgcn_sched_barrier(0);
    __builtin_amdgcn_s_barrier();

    for (int t = 0; t < nt; ++t) {
        const int b = t & 1;
        const unsigned short* Ab0 = As + (b * 2 + 0) * 8192;
        const unsigned short* Bb0 = Bs + (b * 2 + 0) * 8192;
        const unsigned short* Ab1 = As + (b * 2 + 1) * 8192;
        const unsigned short* Bb1 = Bs + (b * 2 + 1) * 8192;
        const bool pf1 = (t + 1 < nt);
        const bool pf2 = (t + 2 < nt);
        short8 af[8], bf0, bf1;

        // ---- phase 1: kk0 x j{0,1} ----
#pragma unroll
        for (int i = 0; i < 8; ++i)
            af[i] = *(const short8*)&Ab0[(wm + i * 16 + fr) * 32 + cq];
        bf0 = *(const short8*)&Bb0[(wn + 0 * 16 + fr) * 32 + cq];
        bf1 = *(const short8*)&Bb0[(wn + 1 * 16 + fr) * 32 + cq];
        if (pf1) STG_B(t + 1, 1, b ^ 1);
        __builtin_amdgcn_s_barrier();
        asm volatile("s_waitcnt lgkmcnt(0)" ::: "memory");
        __builtin_amdgcn_s_setprio(1);
#pragma unroll
        for (int i = 0; i < 8; ++i) {
            acc[i][0] = __builtin_amdgcn_mfma_f32_16x16x32_bf16(af[i], bf0, acc[i][0], 0, 0, 0);
            acc[i][1] = __builtin_amdgcn_mfma_f32_16x16x32_bf16(af[i], bf1, acc[i][1], 0, 0, 0);
        }
        __builtin_amdgcn_s_setprio(0);
        __builtin_amdgcn_s_barrier();

        // ---- phase 2: kk0 x j{2,3} ----
        bf0 = *(const short8*)&Bb0[(wn + 2 * 16 + fr) * 32 + cq];
        bf1 = *(const short8*)&Bb0[(wn + 3 * 16 + fr) * 32 + cq];
        if (pf2) STG_A(t + 2, 0, b);
        __builtin_amdgcn_s_barrier();
        asm volatile("s_waitcnt lgkmcnt(0)" ::: "memory");
        __builtin_amdgcn_s_setprio(1);
#pragma unroll
        for (int i = 0; i < 8; ++i) {
            acc[i][2] = __builtin_amdgcn_mfma_f32_16x16x32_bf16(af[i], bf0, acc[i][2], 0, 0, 0);
            acc[i][3] = __builtin_amdgcn_mfma_f32_16x16x32_bf16(af[i], bf1, acc[i][3], 0, 0, 0);
        }
        __builtin_amdgcn_s_setprio(0);
        __builtin_amdgcn_s_barrier();

        // ---- phase 3: kk1 x j{0,1} ----
#pragma unroll
        for (int i = 0; i < 8; ++i)
            af[i] = *(const short8*)&Ab1[(wm + i * 16 + fr) * 32 + cq];
        bf0 = *(const short8*)&Bb1[(wn + 0 * 16 + fr) * 32 + cq];
        bf1 = *(const short8*)&Bb1[(wn + 1 * 16 + fr) * 32 + cq];
        if (pf2) STG_B(t + 2, 0, b);
        __builtin_amdgcn_s_barrier();
        asm volatile("s_waitcnt lgkmcnt(0)" ::: "memory");
        __builtin_amdgcn_s_setprio(1);
#pragma unroll
        for (int i = 0; i < 8; ++i) {
            acc[i][0] = __builtin_amdgcn_mfma_f32_16x16x32_bf16(af[i], bf0, acc[i][0], 0, 0, 0);
            acc[i][1] = __builtin_amdgcn_mfma_f32_16x16x32_bf16(af[i], bf1, acc[i][1], 0, 0, 0);
        }
        __builtin_amdgcn_s_setprio(0);
        __builtin_amdgcn_s_barrier();

        // ---- phase 4: kk1 x j{2,3} ----
        bf0 = *(const short8*)&Bb1[(wn + 2 * 16 + fr) * 32 + cq];
        bf1 = *(const short8*)&Bb1[(wn + 3 * 16 + fr) * 32 + cq];
        if (pf2) STG_A(t + 2, 1, b);
        __builtin_amdgcn_sched_barrier(0);
        if (pf2) { asm volatile("s_waitcnt vmcnt(6)" ::: "memory"); }
        else     { asm volatile("s_waitcnt vmcnt(0)" ::: "memory"); }
        __builtin_amdgcn_sched_barrier(0);
        __builtin_amdgcn_s_barrier();      // tile t+1 now fully resident
        asm volatile("s_waitcnt lgkmcnt(0)" ::: "memory");
        __builtin_amdgcn_s_setprio(1);
#pragma unroll
        for (int i = 0; i < 8; ++i) {
            acc[i][2] = __builtin_amdgcn_mfma_f32_16x16x32_bf16(af[i], bf0, acc[i][2], 0, 0, 0);
            acc[i][3] = __builtin_amdgcn_mfma_f32_16x16x32_bf16(af[i], bf1, acc[i][3], 0, 0, 0);
        }
        __builtin_amdgcn_s_setprio(0);
        __builtin_amdgcn_s_barrier();
    }
#undef STG_A
#undef STG_B

    // C/D layout: col = lane&15, row = (lane>>4)*4 + reg
    if (STAGE == 1) {
        const int mode = colBase >> 11; // 0=Q, 1=K, 2=V
        if (mode < 2) {
            unsigned short* Co = (mode == 0) ? Cq : Ck;
            const float psgn = (mode == 1) ? -1.953125e-3f : 1.953125e-3f; // ±1/512
#pragma unroll
            for (int j = 0; j < 4; ++j) {
                int gc = (colBase & 2047) + wn + j * 16 + fr;
                float c0 = (float)(gc & ~1);
                float l2sv = log2f((c0 + 819.2f) * (1.0f / 2867.2f)) * psgn;
                float invf = exp2f(c0 * -0.0064881407f); // 10000^(-c0/2048)
                float s1, c1;
                sincosf(invf, &s1, &c1);
#pragma unroll
                for (int i = 0; i < 8; ++i) {
                    int gr0 = rowBase + wm + i * 16 + qd * 4;
                    float fn = (float)(gr0 & (S - 1));
                    float sN, cN;
                    sincosf(fn * invf, &sN, &cN);
#pragma unroll
                    for (int r = 0; r < 4; ++r) {
                        float scale = exp2f(fn * l2sv);
                        float cs = cN * scale, ss = sN * scale;
                        float v = acc[i][j][r];
                        float o = __shfl_xor(v, 1);
                        float res = (gc & 1) ? fmaf(v, cs, o * ss) : fmaf(v, cs, -o * ss);
                        Co[(size_t)(gr0 + r) * H + gc] = f2bf(res);
                        float sn2 = sN * c1 + cN * s1; // rotate by invf
                        cN = cN * c1 - sN * s1;
                        sN = sn2;
                        fn += 1.0f;
                    }
                }
            }
        } else { // V: store transposed Vt[h][8192]
#pragma unroll
            for (int j = 0; j < 4; ++j) {
                int gh = (colBase & 2047) + wn + j * 16 + fr;
#pragma unroll
                for (int i = 0; i < 8; ++i) {
                    int gm0 = rowBase + wm + i * 16 + qd * 4;
                    us4 p;
#pragma unroll
                    for (int r = 0; r < 4; ++r) p[r] = f2bf(acc[i][j][r]);
                    *(us4*)&Cvt[(size_t)gh * 8192 + gm0] = p;
                }
            }
        }
    } else if (STAGE == 3) {
        unsigned short* att = (unsigned short*)Cv + (long long)blockIdx.z * sC;
#pragma unroll
        for (int j = 0; j < 4; ++j) {
            int m = colBase + wn + j * 16 + fr;
#pragma unroll
            for (int i = 0; i < 8; ++i) {
                int n0 = rowBase + wm + i * 16 + qd * 4;
#pragma unroll
                for (int r = 0; r < 4; ++r) {
                    int d = n0 + r - m;
                    float v = (d >= 0) ? acc[i][j][r] * exp2f((float)d * -0.045803598f) : 0.0f;
                    att[(size_t)(n0 + r) * S + m] = f2bf(v);
                }
            }
        }
    } else { // STAGE 4: C rows = n, cols = h -> out[n][h], 64B lane-runs
        float* Co = (float*)Cv + (long long)blockIdx.z * sC;
#pragma unroll
        for (int j = 0; j < 4; ++j) {
            int gh = colBase + wn + j * 16 + fr;
#pragma unroll
            for (int i = 0; i < 8; ++i) {
                int gn0 = rowBase + wm + i * 16 + qd * 4;
#pragma unroll
                for (int r = 0; r < 4; ++r)
                    Co[(size_t)(gn0 + r) * H + gh] = acc[i][j][r];
            }
        }
    }
}

__global__ __launch_bounds__(256)
void cvt_f32_bf16(const float* __restrict__ x, unsigned short* __restrict__ y) {
    int i = blockIdx.x * 256 + threadIdx.x;
    float4 v = ((const float4*)x)[i];
    us4 o = {f2bf(v.x), f2bf(v.y), f2bf(v.z), f2bf(v.w)};
    ((us4*)y)[i] = o;
}

// three W [2048][2048] fp32 -> WtAll [6144][2048] bf16 (transposed per chunk)
__global__ __launch_bounds__(256)
void cvt_transpose3(const float* __restrict__ W0, const float* __restrict__ W1,
                    const float* __restrict__ W2, unsigned short* __restrict__ Wt) {
    __shared__ float t[64][65];
    const float* W = (blockIdx.z == 0) ? W0 : (blockIdx.z == 1) ? W1 : W2;
    unsigned short* Wo = Wt + (size_t)blockIdx.z * 4194304;
    int bx = blockIdx.x * 64, by = blockIdx.y * 64;
    int tx = threadIdx.x & 63, ty = threadIdx.x >> 6;
#pragma unroll
    for (int r = 0; r < 64; r += 4)
        t[ty + r][tx] = W[(size_t)(by + ty + r) * 2048 + bx + tx];
    __syncthreads();
#pragma unroll
    for (int r = 0; r < 64; r += 4)
        Wo[(size_t)(bx + ty + r) * 2048 + by + tx] = f2bf(t[tx][ty + r]);
}

extern "C" void kernel_launch(void* const* d_in, const int* in_sizes, int n_in,
                              void* d_out, int out_size, void* d_ws, size_t ws_size,
                              hipStream_t stream) {
    const int S = 2048, H = 2048;
    const long long MH = 16777216;         // 8192*2048 elements
    const long long HH = 4194304;          // 2048*2048
    const long long SH = (long long)S * H; // per-batch stride
    const long long SS = (long long)S * S;

    const float* X  = (const float*)d_in[0];
    const float* WQ = (const float*)d_in[1];
    const float* WK = (const float*)d_in[2];
    const float* WV = (const float*)d_in[3];
    float* out = (float*)d_out;

    unsigned short* Xb    = (unsigned short*)d_ws;
    unsigned short* WtAll = Xb + MH;        // [6144][2048]
    unsigned short* Qb    = WtAll + 3 * HH;
    unsigned short* Kb    = Qb + MH;
    unsigned short* Vt    = Kb + MH;        // [2048][8192]
    unsigned short* att   = Vt + MH;        // [4][2048][2048]

    cvt_f32_bf16<<<16384, 256, 0, stream>>>(X, Xb);
    cvt_transpose3<<<dim3(32, 32, 3), 256, 0, stream>>>(WQ, WK, WV, WtAll);

    // stage 1: merged QKV projection, M=8192, N=6144
    gemm_bt<1><<<dim3(24, 32), 512, 0, stream>>>(Xb, WtAll, nullptr, Qb, Kb, Vt,
                                                 H, H, H, 0, 0, 0);
    // stage 2: att = (Q K^T) * decay, lower-tri blocks only
    gemm_bt<3><<<dim3(8, 8, 4), 512, 0, stream>>>(Qb, Kb, att, nullptr, nullptr, nullptr,
                                                  H, H, H, SH, SH, SS);
    // stage 3: out = att x V (A=att lda=S; B=Vt ldb=8192, batch col offset 2048)
    gemm_bt<4><<<dim3(8, 8, 4), 512, 0, stream>>>(att, Vt, out, nullptr, nullptr, nullptr,
                                                  S, 8192, S, SS, 2048, SH);
}